// Round 2
// baseline (381.542 us; speedup 1.0000x reference)
//
#include <hip/hip_runtime.h>

// Adaptive downsampler: B=8, C=3, 1024x1024 -> 512x512, K2=9 taps,
// bilinear gather from reflect-padded (pad=1) image, weighted by kernels.
// R1: 4 output pixels per thread -> float4 stream loads/stores + high MLP.
constexpr int B_  = 8;
constexpr int C_  = 3;
constexpr int H_  = 1024;
constexpr int W_  = 1024;
constexpr int HO_ = 512;
constexpr int WO_ = 512;
constexpr int K2_ = 9;
constexpr int KS_ = 3;
constexpr int HP_ = H_ + 2;   // padded height (pad=1)
constexpr int WP_ = W_ + 2;   // padded width
constexpr int PX_ = 4;        // pixels per thread (along ox)

__global__ __launch_bounds__(256) void ds_kernel(
    const float* __restrict__ img,
    const float* __restrict__ kern,
    const float* __restrict__ offh,
    const float* __restrict__ offv,
    const float* __restrict__ unit_p,
    float* __restrict__ out)
{
    const int HWo = HO_ * WO_;                         // 262144
    const int idx = blockIdx.x * 256 + threadIdx.x;    // 524288 threads total

    const int ox = (idx & (WO_ / PX_ - 1)) * PX_;      // 0..508, step 4
    const int oy = (idx >> 7) & (HO_ - 1);
    const int b  = idx >> 16;

    const float unit = unit_p[0];
    const float* imgb = img + (size_t)b * (C_ * H_ * W_);
    const int kbase = b * (K2_ * HWo) + oy * WO_ + ox; // < 2^25, fits int

    float acc[C_][PX_];
#pragma unroll
    for (int c = 0; c < C_; ++c)
#pragma unroll
        for (int p = 0; p < PX_; ++p) acc[c][p] = 0.0f;

#pragma unroll 1
    for (int ky = 0; ky < KS_; ++ky) {
        const float fky = (float)ky;
#pragma unroll
        for (int kx = 0; kx < KS_; ++kx) {
            const int k = ky * KS_ + kx;
            const float4 wk4 = *(const float4*)(kern + kbase + k * HWo);
            const float4 oh4 = *(const float4*)(offh + kbase + k * HWo);
            const float4 ov4 = *(const float4*)(offv + kbase + k * HWo);
            const float wkA[PX_] = {wk4.x, wk4.y, wk4.z, wk4.w};
            const float ohA[PX_] = {oh4.x, oh4.y, oh4.z, oh4.w};
            const float ovA[PX_] = {ov4.x, ov4.y, ov4.z, ov4.w};
            const float fkx = (float)kx;

#pragma unroll
            for (int p = 0; p < PX_; ++p) {
                // (ox+0.5)/WO*W - 0.5 == 2*ox + 0.5 exactly (W/WO == 2)
                const float px = 2.0f * (float)(ox + p) + 0.5f + fkx + ohA[p] * unit;
                const float py = 2.0f * (float)oy       + 0.5f + fky + ovA[p] * unit;

                const float fx = floorf(px);
                const float fy = floorf(py);
                const float a  = px - fx;
                const float bt = py - fy;

                // clip in PADDED coordinates [0, WP-1] / [0, HP-1]
                int xL = (int)fx; xL = xL < 0 ? 0 : (xL > WP_ - 1 ? WP_ - 1 : xL);
                int xR = xL + 1;  xR = xR > WP_ - 1 ? WP_ - 1 : xR;
                int yT = (int)fy; yT = yT < 0 ? 0 : (yT > HP_ - 1 ? HP_ - 1 : yT);
                int yB = yT + 1;  yB = yB > HP_ - 1 ? HP_ - 1 : yB;

                // padded -> original with reflect (pad=1): j=i-1; -1->1; H->H-2
                int xl = xL - 1; xl = (xl < 0) ? -xl : (xl >= W_ ? 2 * W_ - 2 - xl : xl);
                int xr = xR - 1; xr = (xr < 0) ? -xr : (xr >= W_ ? 2 * W_ - 2 - xr : xr);
                int yt = yT - 1; yt = (yt < 0) ? -yt : (yt >= H_ ? 2 * H_ - 2 - yt : yt);
                int yb = yB - 1; yb = (yb < 0) ? -yb : (yb >= H_ ? 2 * H_ - 2 - yb : yb);

                const float wk  = wkA[p];
                const float wtl = (1.0f - a) * (1.0f - bt) * wk;
                const float wtr = a * (1.0f - bt) * wk;
                const float wbl = (1.0f - a) * bt * wk;
                const float wbr = a * bt * wk;

                const int r0 = yt * W_;
                const int r1 = yb * W_;
#pragma unroll
                for (int c = 0; c < C_; ++c) {
                    const float* ch = imgb + c * (H_ * W_);
                    const float tl = ch[r0 + xl];
                    const float tr = ch[r0 + xr];
                    const float bl = ch[r1 + xl];
                    const float br = ch[r1 + xr];
                    acc[c][p] += wtl * tl + wtr * tr + wbl * bl + wbr * br;
                }
            }
        }
    }

    const int obase = b * (C_ * HWo) + oy * WO_ + ox;
#pragma unroll
    for (int c = 0; c < C_; ++c) {
        float4 v = make_float4(acc[c][0], acc[c][1], acc[c][2], acc[c][3]);
        *(float4*)(out + obase + c * HWo) = v;
    }
}

extern "C" void kernel_launch(void* const* d_in, const int* in_sizes, int n_in,
                              void* d_out, int out_size, void* d_ws, size_t ws_size,
                              hipStream_t stream) {
    const float* img  = (const float*)d_in[0];
    const float* kern = (const float*)d_in[1];
    const float* offh = (const float*)d_in[2];
    const float* offv = (const float*)d_in[3];
    const float* unit = (const float*)d_in[4];
    float* out = (float*)d_out;

    const int total = B_ * HO_ * (WO_ / PX_);          // 524,288 threads
    const int block = 256;
    const int grid  = total / block;                   // 2048 blocks
    ds_kernel<<<grid, block, 0, stream>>>(img, kern, offh, offv, unit, out);
}

// Round 3
// 197.893 us; speedup vs baseline: 1.9280x; 1.9280x over previous
//
#include <hip/hip_runtime.h>

// Adaptive downsampler: B=8, C=3, 1024x1024 -> 512x512, K2=9 taps,
// bilinear gather from reflect-padded (pad=1) image, weighted by kernels.
// R2: back to 1 px/thread (lane-contiguous ox -> gather locality),
//     float2 paired x-gathers (|xl-xr| <= 1 always) -> 54 gathers not 108.
constexpr int B_  = 8;
constexpr int C_  = 3;
constexpr int H_  = 1024;
constexpr int W_  = 1024;
constexpr int HO_ = 512;
constexpr int WO_ = 512;
constexpr int K2_ = 9;
constexpr int KS_ = 3;
constexpr int HP_ = H_ + 2;   // padded height (pad=1)
constexpr int WP_ = W_ + 2;   // padded width

__device__ __forceinline__ float2 ld2(const float* p) {
    float2 r;
    __builtin_memcpy(&r, p, sizeof(float2));   // codegen: global_load_dwordx2 (unaligned ok on gfx9+)
    return r;
}

__global__ __launch_bounds__(256) void ds_kernel(
    const float* __restrict__ img,
    const float* __restrict__ kern,
    const float* __restrict__ offh,
    const float* __restrict__ offv,
    const float* __restrict__ unit_p,
    float* __restrict__ out)
{
    const int HWo = HO_ * WO_;                       // 262144
    const int idx = blockIdx.x * 256 + threadIdx.x;

    const int ox = idx & (WO_ - 1);
    const int oy = (idx >> 9) & (HO_ - 1);
    const int b  = idx >> 18;

    const float unit = unit_p[0];
    const float* imgb = img + (size_t)b * (C_ * H_ * W_);
    const int kbase = b * (K2_ * HWo) + oy * WO_ + ox;   // < 2^25, fits int

    // (ox+0.5)/WO*W - 0.5 == 2*ox + 0.5  (exact in fp32; W/WO = 2)
    const float cx = 2.0f * (float)ox + 0.5f;
    const float cy = 2.0f * (float)oy + 0.5f;

    float acc0 = 0.0f, acc1 = 0.0f, acc2 = 0.0f;

#pragma unroll 1
    for (int ky = 0; ky < KS_; ++ky) {
        const float fky = (float)ky;
#pragma unroll
        for (int kx = 0; kx < KS_; ++kx) {
            const int k = ky * KS_ + kx;
            const float wk = kern[kbase + k * HWo];
            const float oh = offh[kbase + k * HWo];
            const float ov = offv[kbase + k * HWo];

            const float px = cx + (float)kx + oh * unit;
            const float py = cy + fky       + ov * unit;

            const float fx = floorf(px);
            const float fy = floorf(py);
            const float a  = px - fx;   // alpha
            const float bt = py - fy;   // beta

            // clip in PADDED coordinates [0, WP-1] / [0, HP-1]
            int xL = (int)fx; xL = xL < 0 ? 0 : (xL > WP_ - 1 ? WP_ - 1 : xL);
            int xR = xL + 1;  xR = xR > WP_ - 1 ? WP_ - 1 : xR;
            int yT = (int)fy; yT = yT < 0 ? 0 : (yT > HP_ - 1 ? HP_ - 1 : yT);
            int yB = yT + 1;  yB = yB > HP_ - 1 ? HP_ - 1 : yB;

            // padded -> original with reflect (pad=1): j=i-1; -1->1; H->H-2
            int xl = xL - 1; xl = (xl < 0) ? -xl : (xl >= W_ ? 2 * W_ - 2 - xl : xl);
            int xr = xR - 1; xr = (xr < 0) ? -xr : (xr >= W_ ? 2 * W_ - 2 - xr : xr);
            int yt = yT - 1; yt = (yt < 0) ? -yt : (yt >= H_ ? 2 * H_ - 2 - yt : yt);
            int yb = yB - 1; yb = (yb < 0) ? -yb : (yb >= H_ ? 2 * H_ - 2 - yb : yb);

            // |xl - xr| <= 1 always (enumerated over all clip/reflect cases),
            // and base = min(xl,xr) <= W-2, so [base, base+1] is in-bounds.
            const int base = xl < xr ? xl : xr;

            // x-weight on element base / base+1 (handles flip & duplicate):
            const float ax0 = ((xl == base) ? (1.0f - a) : 0.0f)
                            + ((xr == base) ? a : 0.0f);
            const float ax1 = 1.0f - ax0;

            const float wt = wk * (1.0f - bt);   // top-row weight
            const float wb = wk * bt;            // bottom-row weight

            const int r0 = yt * W_ + base;
            const int r1 = yb * W_ + base;

            {
                const float* ch = imgb;
                const float2 v = ld2(ch + r0);
                const float2 u = ld2(ch + r1);
                acc0 = fmaf(wt, fmaf(ax0, v.x, ax1 * v.y),
                       fmaf(wb, fmaf(ax0, u.x, ax1 * u.y), acc0));
            }
            {
                const float* ch = imgb + H_ * W_;
                const float2 v = ld2(ch + r0);
                const float2 u = ld2(ch + r1);
                acc1 = fmaf(wt, fmaf(ax0, v.x, ax1 * v.y),
                       fmaf(wb, fmaf(ax0, u.x, ax1 * u.y), acc1));
            }
            {
                const float* ch = imgb + 2 * H_ * W_;
                const float2 v = ld2(ch + r0);
                const float2 u = ld2(ch + r1);
                acc2 = fmaf(wt, fmaf(ax0, v.x, ax1 * v.y),
                       fmaf(wb, fmaf(ax0, u.x, ax1 * u.y), acc2));
            }
        }
    }

    const int obase = b * (C_ * HWo) + oy * WO_ + ox;
    out[obase]           = acc0;
    out[obase + HWo]     = acc1;
    out[obase + 2 * HWo] = acc2;
}

extern "C" void kernel_launch(void* const* d_in, const int* in_sizes, int n_in,
                              void* d_out, int out_size, void* d_ws, size_t ws_size,
                              hipStream_t stream) {
    const float* img  = (const float*)d_in[0];
    const float* kern = (const float*)d_in[1];
    const float* offh = (const float*)d_in[2];
    const float* offv = (const float*)d_in[3];
    const float* unit = (const float*)d_in[4];
    float* out = (float*)d_out;

    const int total = B_ * HO_ * WO_;          // 2,097,152 threads
    const int block = 256;
    const int grid  = total / block;           // 8192 blocks
    ds_kernel<<<grid, block, 0, stream>>>(img, kern, offh, offv, unit, out);
}